// Round 7
// baseline (357.259 us; speedup 1.0000x reference)
//
#include <hip/hip_runtime.h>
#include <hip/hip_bf16.h>

#define NTOK 2048
#define NHEADS 12
#define HDIM 64
#define DIM 768
#define BATCH 4
// exp2-domain: p = exp(QK*0.125 + bias - 16) = exp2((QK + 8*bias - 128) * SC2_)
#define SC2_ 0.18033688011112042f

typedef __attribute__((ext_vector_type(8))) short short8;
typedef __attribute__((ext_vector_type(4))) float f32x4;
typedef __attribute__((ext_vector_type(16))) float f32x16;

__device__ __forceinline__ short f2bf(float f) {
  union { float f; unsigned u; } v; v.f = f;
  unsigned r = v.u + 0x7fffu + ((v.u >> 16) & 1u);
  return (short)(r >> 16);
}

__device__ __forceinline__ f32x4 mfma_bf16(short8 a, short8 b, f32x4 c) {
  return __builtin_amdgcn_mfma_f32_16x16x32_bf16(a, b, c, 0, 0, 0);
}

__device__ __forceinline__ f32x16 mfma32(short8 a, short8 b, f32x16 c) {
  return __builtin_amdgcn_mfma_f32_32x32x16_bf16(a, b, c, 0, 0, 0);
}

__device__ __forceinline__ void gload_lds16(const void* g, void* l) {
  __builtin_amdgcn_global_load_lds((const __attribute__((address_space(1))) void*)g,
                                   (__attribute__((address_space(3))) void*)l, 16, 0, 0);
}

__device__ __forceinline__ float exp2_hw(float x) {
  float r; asm("v_exp_f32 %0, %1" : "=v"(r) : "v"(x)); return r;
}

__device__ __forceinline__ unsigned cvt_pk_bf16(float lo, float hi) {
  unsigned r; asm("v_cvt_pk_bf16_f32 %0, %1, %2" : "=v"(r) : "v"(lo), "v"(hi)); return r;
}

// ---------------- fp32 -> bf16 conversion ----------------
__global__ void cvt_x(const float* __restrict__ src, short* __restrict__ dst) {
  int i = blockIdx.x * 256 + threadIdx.x;
  float4 v = ((const float4*)src)[i];
  short4 o; o.x = f2bf(v.x); o.y = f2bf(v.y); o.z = f2bf(v.z); o.w = f2bf(v.w);
  ((short4*)dst)[i] = o;
}

__global__ void cvt_w(const float* __restrict__ w0, const float* __restrict__ w1,
                      const float* __restrict__ w2, const float* __restrict__ w3,
                      short* __restrict__ d0, short* __restrict__ d1,
                      short* __restrict__ d2, short* __restrict__ d3) {
  int i = blockIdx.x * 256 + threadIdx.x;
  const float* s = blockIdx.y == 0 ? w0 : blockIdx.y == 1 ? w1 : blockIdx.y == 2 ? w2 : w3;
  short* d = blockIdx.y == 0 ? d0 : blockIdx.y == 1 ? d1 : blockIdx.y == 2 ? d2 : d3;
  float4 v = ((const float4*)s)[i];
  short4 o; o.x = f2bf(v.x); o.y = f2bf(v.y); o.z = f2bf(v.z); o.w = f2bf(v.w);
  ((short4*)d)[i] = o;
}

// ---------------- shared GEMM main loop: 128x128 tile, BK=64 ----------------
__device__ __forceinline__ void gemm_mainloop(const short* __restrict__ A,
                                              const short* __restrict__ B,
                                              int mbase, int nbase,
                                              short* As, short* Bs,
                                              f32x4 (&acc)[4][4], int lane, int w) {
  int lr = lane & 15, lg = lane >> 4;
  int wr = w >> 1, wc = w & 1;
  for (int kb = 0; kb < DIM; kb += 64) {
    if (kb) __syncthreads();
#pragma unroll
    for (int c = 0; c < 4; ++c) {
      int row = w * 32 + c * 8 + (lane >> 3);
      int sch = (lane & 7) ^ (row & 7);
      gload_lds16(A + (size_t)(mbase + row) * DIM + kb + sch * 8, (char*)As + w * 4096 + c * 1024);
      gload_lds16(B + (size_t)(nbase + row) * DIM + kb + sch * 8, (char*)Bs + w * 4096 + c * 1024);
    }
    __syncthreads();
#pragma unroll
    for (int ks = 0; ks < 2; ++ks) {
      short8 af[4], bf[4];
#pragma unroll
      for (int i = 0; i < 4; ++i) {
        int row = wr * 64 + i * 16 + lr;
        int ch = (ks * 4 + lg) ^ (row & 7);
        af[i] = *(const short8*)(As + row * 64 + ch * 8);
      }
#pragma unroll
      for (int j = 0; j < 4; ++j) {
        int row = wc * 64 + j * 16 + lr;
        int ch = (ks * 4 + lg) ^ (row & 7);
        bf[j] = *(const short8*)(Bs + row * 64 + ch * 8);
      }
#pragma unroll
      for (int i = 0; i < 4; ++i)
#pragma unroll
        for (int j = 0; j < 4; ++j)
          acc[i][j] = mfma_bf16(af[i], bf[j], acc[i][j]);
    }
  }
}

// ---------------- QKV projection ----------------
__global__ __launch_bounds__(256, 2) void gemm_qkv(const short* __restrict__ xb,
    const short* __restrict__ wq, const short* __restrict__ wk, const short* __restrict__ wv,
    short* __restrict__ Qh, short* __restrict__ Kh, short* __restrict__ Vt) {
  __shared__ __align__(16) short As[128 * 64];
  __shared__ __align__(16) short Bs[128 * 64];
  int nt = blockIdx.x, mt = blockIdx.y, z = blockIdx.z;
  const short* B = z == 0 ? wq : (z == 1 ? wk : wv);
  int tid = threadIdx.x, lane = tid & 63, w = tid >> 6;
  f32x4 acc[4][4] = {};
  gemm_mainloop(xb, B, mt * 128, nt * 128, As, Bs, acc, lane, w);
  int lr = lane & 15, lg = lane >> 4, wr = w >> 1, wc = w & 1;
  if (z < 2) {
    short* dst = z == 0 ? Qh : Kh;
#pragma unroll
    for (int i = 0; i < 4; ++i)
#pragma unroll
      for (int j = 0; j < 4; ++j) {
        int m = mt * 128 + wr * 64 + i * 16 + lg * 4;
        int n = nt * 128 + wc * 64 + j * 16 + lr;
        int bb = m >> 11, nn = m & 2047, hh = n >> 6, d = n & 63;
        size_t base = (((size_t)bb * NHEADS + hh) * NTOK + nn) * HDIM + d;
#pragma unroll
        for (int r = 0; r < 4; ++r)
          dst[base + (size_t)r * HDIM] = f2bf(acc[i][j][r]);
      }
  } else {
#pragma unroll
    for (int i = 0; i < 4; ++i)
#pragma unroll
      for (int j = 0; j < 4; ++j) {
        int m = mt * 128 + wr * 64 + i * 16 + lg * 4;
        int n = nt * 128 + wc * 64 + j * 16 + lr;
        int bb = m >> 11, nn = m & 2047, hh = n >> 6, d = n & 63;
        short4 pk;
        pk.x = f2bf(acc[i][j][0]); pk.y = f2bf(acc[i][j][1]);
        pk.z = f2bf(acc[i][j][2]); pk.w = f2bf(acc[i][j][3]);
        *(short4*)(Vt + (((size_t)bb * NHEADS + hh) * HDIM + d) * NTOK + nn) = pk;
      }
  }
}

// ---------------- fused flash attention ----------------
// 768 blocks (XCD-remapped). 4 waves/block, wave owns 32 q rows, 32x32x16
// MFMA both matmuls operand-swapped; P stays in registers (cvt_pk +
// permlane32_swap). Bias folds into QK accumulator init; bias for tile t+1
// prefetched mid-body (after QK cluster). stage(t+1) issued at body top.
// setprio(1) around MFMA clusters (3 non-lockstep blocks/CU -> role
// diversity, m191/m218b-positive regime). Conflict-free LDS swizzle
// s(row) = (row&7) ^ (row>>3).
__global__ __launch_bounds__(256, 3) void attn_fused(const short* __restrict__ Qh,
    const short* __restrict__ Kh, const short* __restrict__ Vt,
    const float* __restrict__ bias, short* __restrict__ Ob) {
  __shared__ __align__(16) short Ks[2][64 * 64];
  __shared__ __align__(16) short Vs[2][64 * 64];
  int d0 = blockIdx.x;
  int wg = (d0 & 7) * 96 + (d0 >> 3);          // bijective: 768 = 8*96
  int b = wg & 3, qb = (wg >> 2) & 15, h = wg >> 6;
  int tid = threadIdx.x, lane = tid & 63, w = tid >> 6;
  int ql = lane & 31, hi = lane >> 5;

  const short* Q = Qh + ((size_t)b * NHEADS + h) * NTOK * HDIM;
  const short* K = Kh + ((size_t)b * NHEADS + h) * NTOK * HDIM;
  const short* V = Vt + ((size_t)b * NHEADS + h) * HDIM * NTOK;
  int qrow = qb * 128 + w * 32 + ql;
  const float* Bb = bias + ((size_t)h * NTOK + qrow) * NTOK;

  short8 qf[4];
#pragma unroll
  for (int i = 0; i < 4; ++i)
    qf[i] = *(const short8*)(Q + (size_t)qrow * HDIM + i * 16 + hi * 8);

  float psum = 0.f;
  f32x16 oacc[2] = {};

  auto stage = [&](int buf, int kv) {
#pragma unroll
    for (int c = 0; c < 2; ++c) {
      int srow = (lane >> 3) ^ (w * 2 + c);            // (row&7) ^ (row>>3)
      int sch = (lane & 7) ^ srow;
      int row = w * 16 + c * 8 + (lane >> 3);
      gload_lds16(K + (size_t)(kv + row) * HDIM + sch * 8, (char*)Ks[buf] + w * 2048 + c * 1024);
      gload_lds16(V + (size_t)row * NTOK + kv + sch * 8, (char*)Vs[buf] + w * 2048 + c * 1024);
    }
  };

  auto loadBias = [&](int kv, f32x4 (&bv)[8]) {
#pragma unroll
    for (int g = 0; g < 8; ++g)
      bv[g] = *(const f32x4*)(Bb + kv + g * 8 + hi * 4);
  };

  f32x4 bvA[8], bvB[8];
  loadBias(0, bvA);
  stage(0, 0);
  __syncthreads();

  auto body = [&](int t, int cur, f32x4 (&bvc)[8], f32x4 (&bvn)[8]) {
    int kv = t * 64;
    bool more = t < NTOK / 64 - 1;
    if (more) stage(cur ^ 1, kv + 64);  // LDS stage first: drained at barrier

    // bias -> QK accumulator init (bvc resident since last tile, no wait)
    f32x16 sacc[2];
#pragma unroll
    for (int kb = 0; kb < 2; ++kb)
#pragma unroll
      for (int g = 0; g < 4; ++g)
#pragma unroll
        for (int r = 0; r < 4; ++r)
          sacc[kb][g * 4 + r] = fmaf(bvc[kb * 4 + g][r], 8.f, -128.f);

    // S^T = K Q^T : lane holds k=(reg&3)+8*(reg>>2)+4*hi (+kb*32), q=ql
    __builtin_amdgcn_s_setprio(1);
#pragma unroll
    for (int kb = 0; kb < 2; ++kb)
#pragma unroll
      for (int i = 0; i < 4; ++i) {
        int row = kb * 32 + ql;
        int srow = (ql & 7) ^ (kb * 4 + (ql >> 3));
        short8 kf = *(const short8*)(Ks[cur] + row * 64 + (((i * 2 + hi) ^ srow) * 8));
        sacc[kb] = mfma32(kf, qf[i], sacc[kb]);
      }
    __builtin_amdgcn_s_setprio(0);

    // prefetch next tile's bias now: a full softmax+PV phase to land
    if (more) loadBias(kv + 64, bvn);

#pragma unroll
    for (int kb = 0; kb < 2; ++kb) {
      // p = exp2(sacc * SC2)
      float p[16];
#pragma unroll
      for (int rg = 0; rg < 16; ++rg) p[rg] = exp2_hw(sacc[kb][rg] * SC2_);
      float ts = 0.f;
#pragma unroll
      for (int g = 0; g < 4; ++g)
        ts += (p[g * 4] + p[g * 4 + 1]) + (p[g * 4 + 2] + p[g * 4 + 3]);
      psum += ts;
      // pack pairs: Wd[g][tt] covers k = g*8 + 4*hi + 2tt (+kb*32)
      unsigned Wd[4][2];
#pragma unroll
      for (int g = 0; g < 4; ++g)
#pragma unroll
        for (int tt = 0; tt < 2; ++tt)
          Wd[g][tt] = cvt_pk_bf16(p[g * 4 + tt * 2], p[g * 4 + tt * 2 + 1]);

      // PV: rebuild B-frag via permlane32_swap, A = V^T rows from LDS
#pragma unroll
      for (int cc = 0; cc < 2; ++cc) {
        auto r0 = __builtin_amdgcn_permlane32_swap(Wd[cc * 2][0], Wd[cc * 2 + 1][0], false, false);
        auto r1 = __builtin_amdgcn_permlane32_swap(Wd[cc * 2][1], Wd[cc * 2 + 1][1], false, false);
        union { unsigned u[4]; short8 s; } pb;
        pb.u[0] = r0[0]; pb.u[1] = r1[0]; pb.u[2] = r0[1]; pb.u[3] = r1[1];
        __builtin_amdgcn_s_setprio(1);
#pragma unroll
        for (int db = 0; db < 2; ++db) {
          int row = db * 32 + ql;
          int srow = (ql & 7) ^ (db * 4 + (ql >> 3));
          short8 vf = *(const short8*)(Vs[cur] + row * 64 + (((kb * 4 + cc * 2 + hi) ^ srow) * 8));
          oacc[db] = mfma32(vf, pb.s, oacc[db]);
        }
        __builtin_amdgcn_s_setprio(0);
      }
    }

    __syncthreads();
  };

  for (int t = 0; t < NTOK / 64; t += 2) {
    body(t, 0, bvA, bvB);
    body(t + 1, 1, bvB, bvA);
  }

  // epilogue: row-sum finish (one xor-32), normalize, pack, store
  float fs = psum + __shfl_xor(psum, 32);
  float inv = 1.f / fs;
  size_t obase = ((size_t)b * NTOK + qrow) * DIM + h * HDIM;
#pragma unroll
  for (int db = 0; db < 2; ++db)
#pragma unroll
    for (int g = 0; g < 4; ++g) {
      unsigned u0 = cvt_pk_bf16(oacc[db][g * 4] * inv, oacc[db][g * 4 + 1] * inv);
      unsigned u1 = cvt_pk_bf16(oacc[db][g * 4 + 2] * inv, oacc[db][g * 4 + 3] * inv);
      uint2 pk; pk.x = u0; pk.y = u1;
      *(uint2*)(Ob + obase + db * 32 + g * 8 + hi * 4) = pk;
    }
}

// ---------------- output projection ----------------
__global__ __launch_bounds__(256, 2) void gemm_proj(const short* __restrict__ Ob,
    const short* __restrict__ wp, const float* __restrict__ bp, float* __restrict__ out) {
  __shared__ __align__(16) short As[128 * 64];
  __shared__ __align__(16) short Bs[128 * 64];
  int nt = blockIdx.x, mt = blockIdx.y;
  int tid = threadIdx.x, lane = tid & 63, w = tid >> 6;
  f32x4 acc[4][4] = {};
  gemm_mainloop(Ob, wp, mt * 128, nt * 128, As, Bs, acc, lane, w);
  int lr = lane & 15, lg = lane >> 4, wr = w >> 1, wc = w & 1;
#pragma unroll
  for (int j = 0; j < 4; ++j) {
    int n = nt * 128 + wc * 64 + j * 16 + lr;
    float bpv = bp[n];
#pragma unroll
    for (int i = 0; i < 4; ++i) {
      int m = mt * 128 + wr * 64 + i * 16 + lg * 4;
#pragma unroll
      for (int r = 0; r < 4; ++r)
        out[(size_t)(m + r) * DIM + n] = acc[i][j][r] + bpv;
    }
  }
}

extern "C" void kernel_launch(void* const* d_in, const int* in_sizes, int n_in,
                              void* d_out, int out_size, void* d_ws, size_t ws_size,
                              hipStream_t stream) {
  const float* x    = (const float*)d_in[0];
  const float* bias = (const float*)d_in[1];
  const float* Wq   = (const float*)d_in[2];
  const float* Wk   = (const float*)d_in[3];
  const float* Wv   = (const float*)d_in[4];
  const float* Wp   = (const float*)d_in[5];
  const float* bp   = (const float*)d_in[6];
  float* out = (float*)d_out;

  char* ws = (char*)d_ws;
  short* xb  = (short*)(ws);                    // 8192*768 bf16
  short* wqb = (short*)(ws + 12582912);
  short* wkb = (short*)(ws + 13762560);
  short* wvb = (short*)(ws + 14942208);
  short* wpb = (short*)(ws + 16121856);
  short* Qh  = (short*)(ws + 17301504);         // [b][h][n][64]
  short* Kh  = (short*)(ws + 29884416);
  short* Vt  = (short*)(ws + 42467328);         // [b][h][64][n]
  short* Ob  = (short*)(ws + 55050240);         // [b][n][768]

  cvt_x<<<6144, 256, 0, stream>>>(x, xb);
  cvt_w<<<dim3(576, 4), 256, 0, stream>>>(Wq, Wk, Wv, Wp, wqb, wkb, wvb, wpb);
  gemm_qkv<<<dim3(6, 64, 3), 256, 0, stream>>>(xb, wqb, wkb, wvb, Qh, Kh, Vt);
  attn_fused<<<768, 256, 0, stream>>>(Qh, Kh, Vt, bias, Ob);
  gemm_proj<<<dim3(6, 64), 256, 0, stream>>>(Ob, wpb, bp, out);
}

// Round 8
// 351.072 us; speedup vs baseline: 1.0176x; 1.0176x over previous
//
#include <hip/hip_runtime.h>
#include <hip/hip_bf16.h>

#define NTOK 2048
#define NHEADS 12
#define HDIM 64
#define DIM 768
#define BATCH 4
// exp2-domain: p = exp(QK*0.125 + bias - 16) = exp2((QK + 8*bias - 128) * SC2_)
#define SC2_ 0.18033688011112042f

typedef __attribute__((ext_vector_type(8))) short short8;
typedef __attribute__((ext_vector_type(4))) float f32x4;
typedef __attribute__((ext_vector_type(16))) float f32x16;

__device__ __forceinline__ short f2bf(float f) {
  union { float f; unsigned u; } v; v.f = f;
  unsigned r = v.u + 0x7fffu + ((v.u >> 16) & 1u);
  return (short)(r >> 16);
}

__device__ __forceinline__ f32x4 mfma_bf16(short8 a, short8 b, f32x4 c) {
  return __builtin_amdgcn_mfma_f32_16x16x32_bf16(a, b, c, 0, 0, 0);
}

__device__ __forceinline__ f32x16 mfma32(short8 a, short8 b, f32x16 c) {
  return __builtin_amdgcn_mfma_f32_32x32x16_bf16(a, b, c, 0, 0, 0);
}

__device__ __forceinline__ void gload_lds16(const void* g, void* l) {
  __builtin_amdgcn_global_load_lds((const __attribute__((address_space(1))) void*)g,
                                   (__attribute__((address_space(3))) void*)l, 16, 0, 0);
}

__device__ __forceinline__ float exp2_hw(float x) {
  float r; asm("v_exp_f32 %0, %1" : "=v"(r) : "v"(x)); return r;
}

__device__ __forceinline__ unsigned cvt_pk_bf16(float lo, float hi) {
  unsigned r; asm("v_cvt_pk_bf16_f32 %0, %1, %2" : "=v"(r) : "v"(lo), "v"(hi)); return r;
}

// ---------------- fp32 -> bf16 conversion ----------------
__global__ void cvt_x(const float* __restrict__ src, short* __restrict__ dst) {
  int i = blockIdx.x * 256 + threadIdx.x;
  float4 v = ((const float4*)src)[i];
  short4 o; o.x = f2bf(v.x); o.y = f2bf(v.y); o.z = f2bf(v.z); o.w = f2bf(v.w);
  ((short4*)dst)[i] = o;
}

__global__ void cvt_w(const float* __restrict__ w0, const float* __restrict__ w1,
                      const float* __restrict__ w2, const float* __restrict__ w3,
                      short* __restrict__ d0, short* __restrict__ d1,
                      short* __restrict__ d2, short* __restrict__ d3) {
  int i = blockIdx.x * 256 + threadIdx.x;
  const float* s = blockIdx.y == 0 ? w0 : blockIdx.y == 1 ? w1 : blockIdx.y == 2 ? w2 : w3;
  short* d = blockIdx.y == 0 ? d0 : blockIdx.y == 1 ? d1 : blockIdx.y == 2 ? d2 : d3;
  float4 v = ((const float4*)s)[i];
  short4 o; o.x = f2bf(v.x); o.y = f2bf(v.y); o.z = f2bf(v.z); o.w = f2bf(v.w);
  ((short4*)d)[i] = o;
}

// ---------------- shared GEMM main loop: 128x128 tile, BK=64 ----------------
__device__ __forceinline__ void gemm_mainloop(const short* __restrict__ A,
                                              const short* __restrict__ B,
                                              int mbase, int nbase,
                                              short* As, short* Bs,
                                              f32x4 (&acc)[4][4], int lane, int w) {
  int lr = lane & 15, lg = lane >> 4;
  int wr = w >> 1, wc = w & 1;
  for (int kb = 0; kb < DIM; kb += 64) {
    if (kb) __syncthreads();
#pragma unroll
    for (int c = 0; c < 4; ++c) {
      int row = w * 32 + c * 8 + (lane >> 3);
      int sch = (lane & 7) ^ (row & 7);
      gload_lds16(A + (size_t)(mbase + row) * DIM + kb + sch * 8, (char*)As + w * 4096 + c * 1024);
      gload_lds16(B + (size_t)(nbase + row) * DIM + kb + sch * 8, (char*)Bs + w * 4096 + c * 1024);
    }
    __syncthreads();
#pragma unroll
    for (int ks = 0; ks < 2; ++ks) {
      short8 af[4], bf[4];
#pragma unroll
      for (int i = 0; i < 4; ++i) {
        int row = wr * 64 + i * 16 + lr;
        int ch = (ks * 4 + lg) ^ (row & 7);
        af[i] = *(const short8*)(As + row * 64 + ch * 8);
      }
#pragma unroll
      for (int j = 0; j < 4; ++j) {
        int row = wc * 64 + j * 16 + lr;
        int ch = (ks * 4 + lg) ^ (row & 7);
        bf[j] = *(const short8*)(Bs + row * 64 + ch * 8);
      }
#pragma unroll
      for (int i = 0; i < 4; ++i)
#pragma unroll
        for (int j = 0; j < 4; ++j)
          acc[i][j] = mfma_bf16(af[i], bf[j], acc[i][j]);
    }
  }
}

// ---------------- QKV projection ----------------
__global__ __launch_bounds__(256, 2) void gemm_qkv(const short* __restrict__ xb,
    const short* __restrict__ wq, const short* __restrict__ wk, const short* __restrict__ wv,
    short* __restrict__ Qh, short* __restrict__ Kh, short* __restrict__ Vt) {
  __shared__ __align__(16) short As[128 * 64];
  __shared__ __align__(16) short Bs[128 * 64];
  int nt = blockIdx.x, mt = blockIdx.y, z = blockIdx.z;
  const short* B = z == 0 ? wq : (z == 1 ? wk : wv);
  int tid = threadIdx.x, lane = tid & 63, w = tid >> 6;
  f32x4 acc[4][4] = {};
  gemm_mainloop(xb, B, mt * 128, nt * 128, As, Bs, acc, lane, w);
  int lr = lane & 15, lg = lane >> 4, wr = w >> 1, wc = w & 1;
  if (z < 2) {
    short* dst = z == 0 ? Qh : Kh;
#pragma unroll
    for (int i = 0; i < 4; ++i)
#pragma unroll
      for (int j = 0; j < 4; ++j) {
        int m = mt * 128 + wr * 64 + i * 16 + lg * 4;
        int n = nt * 128 + wc * 64 + j * 16 + lr;
        int bb = m >> 11, nn = m & 2047, hh = n >> 6, d = n & 63;
        size_t base = (((size_t)bb * NHEADS + hh) * NTOK + nn) * HDIM + d;
#pragma unroll
        for (int r = 0; r < 4; ++r)
          dst[base + (size_t)r * HDIM] = f2bf(acc[i][j][r]);
      }
  } else {
#pragma unroll
    for (int i = 0; i < 4; ++i)
#pragma unroll
      for (int j = 0; j < 4; ++j) {
        int m = mt * 128 + wr * 64 + i * 16 + lg * 4;
        int n = nt * 128 + wc * 64 + j * 16 + lr;
        int bb = m >> 11, nn = m & 2047, hh = n >> 6, d = n & 63;
        short4 pk;
        pk.x = f2bf(acc[i][j][0]); pk.y = f2bf(acc[i][j][1]);
        pk.z = f2bf(acc[i][j][2]); pk.w = f2bf(acc[i][j][3]);
        *(short4*)(Vt + (((size_t)bb * NHEADS + hh) * HDIM + d) * NTOK + nn) = pk;
      }
  }
}

// ---------------- fused flash attention ----------------
// 768 blocks (XCD-remapped, b fastest). 4 waves/block, wave owns 32 q rows,
// 32x32x16 MFMA both matmuls operand-swapped; P stays in registers (cvt_pk +
// permlane32_swap). Bias folds into QK accumulator C-init; bias for t+1
// prefetched after the QK cluster into NAMED register arrays via a MACRO body
// (no lambda-reference arrays: they are address-taken -> scratch spill, the
// r6/r7 regression). Conflict-free LDS swizzle s(row) = (row&7)^(row>>3).

#define ATTN_BODY(T, CUR, BVC, BVN)                                           \
  {                                                                           \
    const int kv = (T) * 64;                                                  \
    if ((T) < NTOK / 64 - 1) {                                                \
      _Pragma("unroll")                                                       \
      for (int c = 0; c < 2; ++c) {                                           \
        int srow = (lane >> 3) ^ (w * 2 + c);                                 \
        int sch = (lane & 7) ^ srow;                                          \
        int row = w * 16 + c * 8 + (lane >> 3);                               \
        gload_lds16(K + (size_t)(kv + 64 + row) * HDIM + sch * 8,             \
                    (char*)Ks[(CUR) ^ 1] + w * 2048 + c * 1024);              \
        gload_lds16(V + (size_t)row * NTOK + kv + 64 + sch * 8,               \
                    (char*)Vs[(CUR) ^ 1] + w * 2048 + c * 1024);              \
      }                                                                       \
    }                                                                         \
    f32x16 sacc0, sacc1;                                                      \
    _Pragma("unroll")                                                         \
    for (int g = 0; g < 4; ++g) {                                             \
      _Pragma("unroll")                                                       \
      for (int r = 0; r < 4; ++r) {                                           \
        sacc0[g * 4 + r] = fmaf(BVC[g][r], 8.f, -128.f);                      \
        sacc1[g * 4 + r] = fmaf(BVC[4 + g][r], 8.f, -128.f);                  \
      }                                                                       \
    }                                                                         \
    __builtin_amdgcn_s_setprio(1);                                            \
    _Pragma("unroll")                                                         \
    for (int i = 0; i < 4; ++i) {                                             \
      int srow0 = (ql & 7) ^ (ql >> 3);                                       \
      int srow1 = (ql & 7) ^ (4 + (ql >> 3));                                 \
      short8 kf0 = *(const short8*)(Ks[CUR] + ql * 64 + (((i * 2 + hi) ^ srow0) * 8)); \
      short8 kf1 = *(const short8*)(Ks[CUR] + (32 + ql) * 64 + (((i * 2 + hi) ^ srow1) * 8)); \
      sacc0 = mfma32(kf0, qf[i], sacc0);                                      \
      sacc1 = mfma32(kf1, qf[i], sacc1);                                      \
    }                                                                         \
    __builtin_amdgcn_s_setprio(0);                                            \
    if ((T) < NTOK / 64 - 1) {                                                \
      _Pragma("unroll")                                                       \
      for (int g = 0; g < 8; ++g)                                             \
        BVN[g] = *(const f32x4*)(Bb + kv + 64 + g * 8 + hi * 4);              \
    }                                                                         \
    _Pragma("unroll")                                                         \
    for (int kb = 0; kb < 2; ++kb) {                                          \
      float p[16];                                                            \
      _Pragma("unroll")                                                       \
      for (int rg = 0; rg < 16; ++rg)                                         \
        p[rg] = exp2_hw((kb ? sacc1[rg] : sacc0[rg]) * SC2_);                 \
      float ts = 0.f;                                                         \
      _Pragma("unroll")                                                       \
      for (int g = 0; g < 4; ++g)                                             \
        ts += (p[g * 4] + p[g * 4 + 1]) + (p[g * 4 + 2] + p[g * 4 + 3]);      \
      psum += ts;                                                             \
      unsigned Wd[4][2];                                                      \
      _Pragma("unroll")                                                       \
      for (int g = 0; g < 4; ++g) {                                           \
        Wd[g][0] = cvt_pk_bf16(p[g * 4], p[g * 4 + 1]);                       \
        Wd[g][1] = cvt_pk_bf16(p[g * 4 + 2], p[g * 4 + 3]);                   \
      }                                                                       \
      _Pragma("unroll")                                                       \
      for (int cc = 0; cc < 2; ++cc) {                                        \
        auto r0 = __builtin_amdgcn_permlane32_swap(Wd[cc * 2][0], Wd[cc * 2 + 1][0], false, false); \
        auto r1 = __builtin_amdgcn_permlane32_swap(Wd[cc * 2][1], Wd[cc * 2 + 1][1], false, false); \
        union { unsigned u[4]; short8 s; } pb;                                \
        pb.u[0] = r0[0]; pb.u[1] = r1[0]; pb.u[2] = r0[1]; pb.u[3] = r1[1];   \
        __builtin_amdgcn_s_setprio(1);                                        \
        {                                                                     \
          int srow0 = (ql & 7) ^ (ql >> 3);                                   \
          int srow1 = (ql & 7) ^ (4 + (ql >> 3));                             \
          short8 vf0 = *(const short8*)(Vs[CUR] + ql * 64 + (((kb * 4 + cc * 2 + hi) ^ srow0) * 8)); \
          short8 vf1 = *(const short8*)(Vs[CUR] + (32 + ql) * 64 + (((kb * 4 + cc * 2 + hi) ^ srow1) * 8)); \
          oacc0 = mfma32(vf0, pb.s, oacc0);                                   \
          oacc1 = mfma32(vf1, pb.s, oacc1);                                   \
        }                                                                     \
        __builtin_amdgcn_s_setprio(0);                                        \
      }                                                                       \
    }                                                                         \
    __syncthreads();                                                          \
  }

__global__ __launch_bounds__(256, 3) void attn_fused(const short* __restrict__ Qh,
    const short* __restrict__ Kh, const short* __restrict__ Vt,
    const float* __restrict__ bias, short* __restrict__ Ob) {
  __shared__ __align__(16) short Ks[2][64 * 64];
  __shared__ __align__(16) short Vs[2][64 * 64];
  int d0 = blockIdx.x;
  int wg = (d0 & 7) * 96 + (d0 >> 3);          // bijective: 768 = 8*96
  int b = wg & 3, qb = (wg >> 2) & 15, h = wg >> 6;
  int tid = threadIdx.x, lane = tid & 63, w = tid >> 6;
  int ql = lane & 31, hi = lane >> 5;

  const short* Q = Qh + ((size_t)b * NHEADS + h) * NTOK * HDIM;
  const short* K = Kh + ((size_t)b * NHEADS + h) * NTOK * HDIM;
  const short* V = Vt + ((size_t)b * NHEADS + h) * HDIM * NTOK;
  int qrow = qb * 128 + w * 32 + ql;
  const float* Bb = bias + ((size_t)h * NTOK + qrow) * NTOK;

  short8 qf[4];
#pragma unroll
  for (int i = 0; i < 4; ++i)
    qf[i] = *(const short8*)(Q + (size_t)qrow * HDIM + i * 16 + hi * 8);

  float psum = 0.f;
  f32x16 oacc0 = {}, oacc1 = {};

  // prologue: bias tile 0 + K/V tile 0
  f32x4 bvA[8], bvB[8];
#pragma unroll
  for (int g = 0; g < 8; ++g)
    bvA[g] = *(const f32x4*)(Bb + g * 8 + hi * 4);
#pragma unroll
  for (int c = 0; c < 2; ++c) {
    int srow = (lane >> 3) ^ (w * 2 + c);
    int sch = (lane & 7) ^ srow;
    int row = w * 16 + c * 8 + (lane >> 3);
    gload_lds16(K + (size_t)row * HDIM + sch * 8, (char*)Ks[0] + w * 2048 + c * 1024);
    gload_lds16(V + (size_t)row * NTOK + sch * 8, (char*)Vs[0] + w * 2048 + c * 1024);
  }
  __syncthreads();

  for (int t = 0; t < NTOK / 64; t += 2) {
    ATTN_BODY(t, 0, bvA, bvB)
    ATTN_BODY(t + 1, 1, bvB, bvA)
  }

  // epilogue: row-sum finish (one xor-32), normalize, pack, store
  float fs = psum + __shfl_xor(psum, 32);
  float inv = 1.f / fs;
  size_t obase = ((size_t)b * NTOK + qrow) * DIM + h * HDIM;
#pragma unroll
  for (int g = 0; g < 4; ++g) {
    unsigned u0 = cvt_pk_bf16(oacc0[g * 4] * inv, oacc0[g * 4 + 1] * inv);
    unsigned u1 = cvt_pk_bf16(oacc0[g * 4 + 2] * inv, oacc0[g * 4 + 3] * inv);
    uint2 pk0; pk0.x = u0; pk0.y = u1;
    *(uint2*)(Ob + obase + g * 8 + hi * 4) = pk0;
    unsigned u2 = cvt_pk_bf16(oacc1[g * 4] * inv, oacc1[g * 4 + 1] * inv);
    unsigned u3 = cvt_pk_bf16(oacc1[g * 4 + 2] * inv, oacc1[g * 4 + 3] * inv);
    uint2 pk1; pk1.x = u2; pk1.y = u3;
    *(uint2*)(Ob + obase + 32 + g * 8 + hi * 4) = pk1;
  }
}

// ---------------- output projection ----------------
__global__ __launch_bounds__(256, 2) void gemm_proj(const short* __restrict__ Ob,
    const short* __restrict__ wp, const float* __restrict__ bp, float* __restrict__ out) {
  __shared__ __align__(16) short As[128 * 64];
  __shared__ __align__(16) short Bs[128 * 64];
  int nt = blockIdx.x, mt = blockIdx.y;
  int tid = threadIdx.x, lane = tid & 63, w = tid >> 6;
  f32x4 acc[4][4] = {};
  gemm_mainloop(Ob, wp, mt * 128, nt * 128, As, Bs, acc, lane, w);
  int lr = lane & 15, lg = lane >> 4, wr = w >> 1, wc = w & 1;
#pragma unroll
  for (int j = 0; j < 4; ++j) {
    int n = nt * 128 + wc * 64 + j * 16 + lr;
    float bpv = bp[n];
#pragma unroll
    for (int i = 0; i < 4; ++i) {
      int m = mt * 128 + wr * 64 + i * 16 + lg * 4;
#pragma unroll
      for (int r = 0; r < 4; ++r)
        out[(size_t)(m + r) * DIM + n] = acc[i][j][r] + bpv;
    }
  }
}

extern "C" void kernel_launch(void* const* d_in, const int* in_sizes, int n_in,
                              void* d_out, int out_size, void* d_ws, size_t ws_size,
                              hipStream_t stream) {
  const float* x    = (const float*)d_in[0];
  const float* bias = (const float*)d_in[1];
  const float* Wq   = (const float*)d_in[2];
  const float* Wk   = (const float*)d_in[3];
  const float* Wv   = (const float*)d_in[4];
  const float* Wp   = (const float*)d_in[5];
  const float* bp   = (const float*)d_in[6];
  float* out = (float*)d_out;

  char* ws = (char*)d_ws;
  short* xb  = (short*)(ws);                    // 8192*768 bf16
  short* wqb = (short*)(ws + 12582912);
  short* wkb = (short*)(ws + 13762560);
  short* wvb = (short*)(ws + 14942208);
  short* wpb = (short*)(ws + 16121856);
  short* Qh  = (short*)(ws + 17301504);         // [b][h][n][64]
  short* Kh  = (short*)(ws + 29884416);
  short* Vt  = (short*)(ws + 42467328);         // [b][h][64][n]
  short* Ob  = (short*)(ws + 55050240);         // [b][n][768]

  cvt_x<<<6144, 256, 0, stream>>>(x, xb);
  cvt_w<<<dim3(576, 4), 256, 0, stream>>>(Wq, Wk, Wv, Wp, wqb, wkb, wvb, wpb);
  gemm_qkv<<<dim3(6, 64, 3), 256, 0, stream>>>(xb, wqb, wkb, wvb, Qh, Kh, Vt);
  attn_fused<<<768, 256, 0, stream>>>(Qh, Kh, Vt, bias, Ob);
  gemm_proj<<<dim3(6, 64), 256, 0, stream>>>(Ob, wpb, bp, out);
}

// Round 9
// 214.367 us; speedup vs baseline: 1.6666x; 1.6377x over previous
//
#include <hip/hip_runtime.h>
#include <hip/hip_bf16.h>

#define NTOK 2048
#define NHEADS 12
#define HDIM 64
#define DIM 768
#define BATCH 4
// exp2-domain: p = exp(QK*0.125 + bias - 16) = exp2(QK*SC2 + bias*LOG2E - SHIFT2)
#define SC2_    0.18033688011112042f
#define LOG2E_  1.4426950408889634f
#define SHIFT2_ 23.083120654223415f

typedef __attribute__((ext_vector_type(8))) short short8;
typedef __attribute__((ext_vector_type(4))) float f32x4;
typedef __attribute__((ext_vector_type(16))) float f32x16;

__device__ __forceinline__ short f2bf(float f) {
  union { float f; unsigned u; } v; v.f = f;
  unsigned r = v.u + 0x7fffu + ((v.u >> 16) & 1u);
  return (short)(r >> 16);
}

__device__ __forceinline__ f32x4 mfma_bf16(short8 a, short8 b, f32x4 c) {
  return __builtin_amdgcn_mfma_f32_16x16x32_bf16(a, b, c, 0, 0, 0);
}

__device__ __forceinline__ f32x16 mfma32(short8 a, short8 b, f32x16 c) {
  return __builtin_amdgcn_mfma_f32_32x32x16_bf16(a, b, c, 0, 0, 0);
}

__device__ __forceinline__ void gload_lds16(const void* g, void* l) {
  __builtin_amdgcn_global_load_lds((const __attribute__((address_space(1))) void*)g,
                                   (__attribute__((address_space(3))) void*)l, 16, 0, 0);
}

__device__ __forceinline__ float exp2_hw(float x) {
  float r; asm("v_exp_f32 %0, %1" : "=v"(r) : "v"(x)); return r;
}

__device__ __forceinline__ unsigned cvt_pk_bf16(float lo, float hi) {
  unsigned r; asm("v_cvt_pk_bf16_f32 %0, %1, %2" : "=v"(r) : "v"(lo), "v"(hi)); return r;
}

// ---------------- fp32 -> bf16 conversion ----------------
__global__ void cvt_x(const float* __restrict__ src, short* __restrict__ dst) {
  int i = blockIdx.x * 256 + threadIdx.x;
  float4 v = ((const float4*)src)[i];
  short4 o; o.x = f2bf(v.x); o.y = f2bf(v.y); o.z = f2bf(v.z); o.w = f2bf(v.w);
  ((short4*)dst)[i] = o;
}

__global__ void cvt_w(const float* __restrict__ w0, const float* __restrict__ w1,
                      const float* __restrict__ w2, const float* __restrict__ w3,
                      short* __restrict__ d0, short* __restrict__ d1,
                      short* __restrict__ d2, short* __restrict__ d3) {
  int i = blockIdx.x * 256 + threadIdx.x;
  const float* s = blockIdx.y == 0 ? w0 : blockIdx.y == 1 ? w1 : blockIdx.y == 2 ? w2 : w3;
  short* d = blockIdx.y == 0 ? d0 : blockIdx.y == 1 ? d1 : blockIdx.y == 2 ? d2 : d3;
  float4 v = ((const float4*)s)[i];
  short4 o; o.x = f2bf(v.x); o.y = f2bf(v.y); o.z = f2bf(v.z); o.w = f2bf(v.w);
  ((short4*)d)[i] = o;
}

// ---------------- shared GEMM main loop: 128x128 tile, BK=64 ----------------
__device__ __forceinline__ void gemm_mainloop(const short* __restrict__ A,
                                              const short* __restrict__ B,
                                              int mbase, int nbase,
                                              short* As, short* Bs,
                                              f32x4 (&acc)[4][4], int lane, int w) {
  int lr = lane & 15, lg = lane >> 4;
  int wr = w >> 1, wc = w & 1;
  for (int kb = 0; kb < DIM; kb += 64) {
    if (kb) __syncthreads();
#pragma unroll
    for (int c = 0; c < 4; ++c) {
      int row = w * 32 + c * 8 + (lane >> 3);
      int sch = (lane & 7) ^ (row & 7);
      gload_lds16(A + (size_t)(mbase + row) * DIM + kb + sch * 8, (char*)As + w * 4096 + c * 1024);
      gload_lds16(B + (size_t)(nbase + row) * DIM + kb + sch * 8, (char*)Bs + w * 4096 + c * 1024);
    }
    __syncthreads();
#pragma unroll
    for (int ks = 0; ks < 2; ++ks) {
      short8 af[4], bf[4];
#pragma unroll
      for (int i = 0; i < 4; ++i) {
        int row = wr * 64 + i * 16 + lr;
        int ch = (ks * 4 + lg) ^ (row & 7);
        af[i] = *(const short8*)(As + row * 64 + ch * 8);
      }
#pragma unroll
      for (int j = 0; j < 4; ++j) {
        int row = wc * 64 + j * 16 + lr;
        int ch = (ks * 4 + lg) ^ (row & 7);
        bf[j] = *(const short8*)(Bs + row * 64 + ch * 8);
      }
#pragma unroll
      for (int i = 0; i < 4; ++i)
#pragma unroll
        for (int j = 0; j < 4; ++j)
          acc[i][j] = mfma_bf16(af[i], bf[j], acc[i][j]);
    }
  }
}

// ---------------- QKV projection ----------------
__global__ __launch_bounds__(256, 2) void gemm_qkv(const short* __restrict__ xb,
    const short* __restrict__ wq, const short* __restrict__ wk, const short* __restrict__ wv,
    short* __restrict__ Qh, short* __restrict__ Kh, short* __restrict__ Vt) {
  __shared__ __align__(16) short As[128 * 64];
  __shared__ __align__(16) short Bs[128 * 64];
  int nt = blockIdx.x, mt = blockIdx.y, z = blockIdx.z;
  const short* B = z == 0 ? wq : (z == 1 ? wk : wv);
  int tid = threadIdx.x, lane = tid & 63, w = tid >> 6;
  f32x4 acc[4][4] = {};
  gemm_mainloop(xb, B, mt * 128, nt * 128, As, Bs, acc, lane, w);
  int lr = lane & 15, lg = lane >> 4, wr = w >> 1, wc = w & 1;
  if (z < 2) {
    short* dst = z == 0 ? Qh : Kh;
#pragma unroll
    for (int i = 0; i < 4; ++i)
#pragma unroll
      for (int j = 0; j < 4; ++j) {
        int m = mt * 128 + wr * 64 + i * 16 + lg * 4;
        int n = nt * 128 + wc * 64 + j * 16 + lr;
        int bb = m >> 11, nn = m & 2047, hh = n >> 6, d = n & 63;
        size_t base = (((size_t)bb * NHEADS + hh) * NTOK + nn) * HDIM + d;
#pragma unroll
        for (int r = 0; r < 4; ++r)
          dst[base + (size_t)r * HDIM] = f2bf(acc[i][j][r]);
      }
  } else {
#pragma unroll
    for (int i = 0; i < 4; ++i)
#pragma unroll
      for (int j = 0; j < 4; ++j) {
        int m = mt * 128 + wr * 64 + i * 16 + lg * 4;
        int n = nt * 128 + wc * 64 + j * 16 + lr;
        int bb = m >> 11, nn = m & 2047, hh = n >> 6, d = n & 63;
        short4 pk;
        pk.x = f2bf(acc[i][j][0]); pk.y = f2bf(acc[i][j][1]);
        pk.z = f2bf(acc[i][j][2]); pk.w = f2bf(acc[i][j][3]);
        *(short4*)(Vt + (((size_t)bb * NHEADS + hh) * HDIM + d) * NTOK + nn) = pk;
      }
  }
}

// ---------------- fused flash attention ----------------
// 768 blocks (XCD-remapped, b fastest). 4 waves/block, wave owns 32 q rows,
// 32x32x16 MFMA both matmuls operand-swapped; P stays in registers (cvt_pk +
// permlane32_swap). DEFERRED bias: QK runs with C=0; bias loads issued at
// body top (before the stage loads so their waitcnt doesn't drain the stage),
// folded in at the exp stage -> bias regs live only within one body, no
// cross-tile arrays, no spill (the r6-r8 regression). Conflict-free LDS
// swizzle s(row) = (row&7)^(row>>3).

#define ATTN_BODY(T, CUR)                                                     \
  {                                                                           \
    const int kv = (T) * 64;                                                  \
    f32x4 bv[8];                                                              \
    _Pragma("unroll")                                                         \
    for (int g = 0; g < 8; ++g)                                               \
      bv[g] = *(const f32x4*)(Bb + kv + g * 8 + hi * 4);                      \
    if ((T) < NTOK / 64 - 1) {                                                \
      _Pragma("unroll")                                                       \
      for (int c = 0; c < 2; ++c) {                                           \
        int srow = (lane >> 3) ^ (w * 2 + c);                                 \
        int sch = (lane & 7) ^ srow;                                          \
        int row = w * 16 + c * 8 + (lane >> 3);                               \
        gload_lds16(K + (size_t)(kv + 64 + row) * HDIM + sch * 8,             \
                    (char*)Ks[(CUR) ^ 1] + w * 2048 + c * 1024);              \
        gload_lds16(V + (size_t)row * NTOK + kv + 64 + sch * 8,               \
                    (char*)Vs[(CUR) ^ 1] + w * 2048 + c * 1024);              \
      }                                                                       \
    }                                                                         \
    f32x16 sacc0 = {}, sacc1 = {};                                            \
    __builtin_amdgcn_s_setprio(1);                                            \
    _Pragma("unroll")                                                         \
    for (int i = 0; i < 4; ++i) {                                             \
      int srow0 = (ql & 7) ^ (ql >> 3);                                       \
      int srow1 = (ql & 7) ^ (4 + (ql >> 3));                                 \
      short8 kf0 = *(const short8*)(Ks[CUR] + ql * 64 + (((i * 2 + hi) ^ srow0) * 8)); \
      short8 kf1 = *(const short8*)(Ks[CUR] + (32 + ql) * 64 + (((i * 2 + hi) ^ srow1) * 8)); \
      sacc0 = mfma32(kf0, qf[i], sacc0);                                      \
      sacc1 = mfma32(kf1, qf[i], sacc1);                                      \
    }                                                                         \
    __builtin_amdgcn_s_setprio(0);                                            \
    _Pragma("unroll")                                                         \
    for (int kb = 0; kb < 2; ++kb) {                                          \
      float p[16];                                                            \
      _Pragma("unroll")                                                       \
      for (int rg = 0; rg < 16; ++rg) {                                       \
        float tb = fmaf(bv[kb * 4 + (rg >> 2)][rg & 3], LOG2E_, -SHIFT2_);    \
        p[rg] = exp2_hw(fmaf((kb ? sacc1[rg] : sacc0[rg]), SC2_, tb));        \
      }                                                                       \
      float ts = 0.f;                                                         \
      _Pragma("unroll")                                                       \
      for (int g = 0; g < 4; ++g)                                             \
        ts += (p[g * 4] + p[g * 4 + 1]) + (p[g * 4 + 2] + p[g * 4 + 3]);      \
      psum += ts;                                                             \
      unsigned Wd[4][2];                                                      \
      _Pragma("unroll")                                                       \
      for (int g = 0; g < 4; ++g) {                                           \
        Wd[g][0] = cvt_pk_bf16(p[g * 4], p[g * 4 + 1]);                       \
        Wd[g][1] = cvt_pk_bf16(p[g * 4 + 2], p[g * 4 + 3]);                   \
      }                                                                       \
      _Pragma("unroll")                                                       \
      for (int cc = 0; cc < 2; ++cc) {                                        \
        auto r0 = __builtin_amdgcn_permlane32_swap(Wd[cc * 2][0], Wd[cc * 2 + 1][0], false, false); \
        auto r1 = __builtin_amdgcn_permlane32_swap(Wd[cc * 2][1], Wd[cc * 2 + 1][1], false, false); \
        union { unsigned u[4]; short8 s; } pb;                                \
        pb.u[0] = r0[0]; pb.u[1] = r1[0]; pb.u[2] = r0[1]; pb.u[3] = r1[1];   \
        __builtin_amdgcn_s_setprio(1);                                        \
        {                                                                     \
          int srow0 = (ql & 7) ^ (ql >> 3);                                   \
          int srow1 = (ql & 7) ^ (4 + (ql >> 3));                             \
          short8 vf0 = *(const short8*)(Vs[CUR] + ql * 64 + (((kb * 4 + cc * 2 + hi) ^ srow0) * 8)); \
          short8 vf1 = *(const short8*)(Vs[CUR] + (32 + ql) * 64 + (((kb * 4 + cc * 2 + hi) ^ srow1) * 8)); \
          oacc0 = mfma32(vf0, pb.s, oacc0);                                   \
          oacc1 = mfma32(vf1, pb.s, oacc1);                                   \
        }                                                                     \
        __builtin_amdgcn_s_setprio(0);                                        \
      }                                                                       \
    }                                                                         \
    __syncthreads();                                                          \
  }

__global__ __launch_bounds__(256, 3) void attn_fused(const short* __restrict__ Qh,
    const short* __restrict__ Kh, const short* __restrict__ Vt,
    const float* __restrict__ bias, short* __restrict__ Ob) {
  __shared__ __align__(16) short Ks[2][64 * 64];
  __shared__ __align__(16) short Vs[2][64 * 64];
  int d0 = blockIdx.x;
  int wg = (d0 & 7) * 96 + (d0 >> 3);          // bijective: 768 = 8*96
  int b = wg & 3, qb = (wg >> 2) & 15, h = wg >> 6;
  int tid = threadIdx.x, lane = tid & 63, w = tid >> 6;
  int ql = lane & 31, hi = lane >> 5;

  const short* Q = Qh + ((size_t)b * NHEADS + h) * NTOK * HDIM;
  const short* K = Kh + ((size_t)b * NHEADS + h) * NTOK * HDIM;
  const short* V = Vt + ((size_t)b * NHEADS + h) * HDIM * NTOK;
  int qrow = qb * 128 + w * 32 + ql;
  const float* Bb = bias + ((size_t)h * NTOK + qrow) * NTOK;

  short8 qf[4];
#pragma unroll
  for (int i = 0; i < 4; ++i)
    qf[i] = *(const short8*)(Q + (size_t)qrow * HDIM + i * 16 + hi * 8);

  float psum = 0.f;
  f32x16 oacc0 = {}, oacc1 = {};

  // prologue: K/V tile 0
#pragma unroll
  for (int c = 0; c < 2; ++c) {
    int srow = (lane >> 3) ^ (w * 2 + c);
    int sch = (lane & 7) ^ srow;
    int row = w * 16 + c * 8 + (lane >> 3);
    gload_lds16(K + (size_t)row * HDIM + sch * 8, (char*)Ks[0] + w * 2048 + c * 1024);
    gload_lds16(V + (size_t)row * NTOK + sch * 8, (char*)Vs[0] + w * 2048 + c * 1024);
  }
  __syncthreads();

  for (int t = 0; t < NTOK / 64; t += 2) {
    ATTN_BODY(t, 0)
    ATTN_BODY(t + 1, 1)
  }

  // epilogue: row-sum finish (one xor-32), normalize, pack, store
  float fs = psum + __shfl_xor(psum, 32);
  float inv = 1.f / fs;
  size_t obase = ((size_t)b * NTOK + qrow) * DIM + h * HDIM;
#pragma unroll
  for (int g = 0; g < 4; ++g) {
    unsigned u0 = cvt_pk_bf16(oacc0[g * 4] * inv, oacc0[g * 4 + 1] * inv);
    unsigned u1 = cvt_pk_bf16(oacc0[g * 4 + 2] * inv, oacc0[g * 4 + 3] * inv);
    uint2 pk0; pk0.x = u0; pk0.y = u1;
    *(uint2*)(Ob + obase + g * 8 + hi * 4) = pk0;
    unsigned u2 = cvt_pk_bf16(oacc1[g * 4] * inv, oacc1[g * 4 + 1] * inv);
    unsigned u3 = cvt_pk_bf16(oacc1[g * 4 + 2] * inv, oacc1[g * 4 + 3] * inv);
    uint2 pk1; pk1.x = u2; pk1.y = u3;
    *(uint2*)(Ob + obase + 32 + g * 8 + hi * 4) = pk1;
  }
}

// ---------------- output projection ----------------
__global__ __launch_bounds__(256, 2) void gemm_proj(const short* __restrict__ Ob,
    const short* __restrict__ wp, const float* __restrict__ bp, float* __restrict__ out) {
  __shared__ __align__(16) short As[128 * 64];
  __shared__ __align__(16) short Bs[128 * 64];
  int nt = blockIdx.x, mt = blockIdx.y;
  int tid = threadIdx.x, lane = tid & 63, w = tid >> 6;
  f32x4 acc[4][4] = {};
  gemm_mainloop(Ob, wp, mt * 128, nt * 128, As, Bs, acc, lane, w);
  int lr = lane & 15, lg = lane >> 4, wr = w >> 1, wc = w & 1;
#pragma unroll
  for (int j = 0; j < 4; ++j) {
    int n = nt * 128 + wc * 64 + j * 16 + lr;
    float bpv = bp[n];
#pragma unroll
    for (int i = 0; i < 4; ++i) {
      int m = mt * 128 + wr * 64 + i * 16 + lg * 4;
#pragma unroll
      for (int r = 0; r < 4; ++r)
        out[(size_t)(m + r) * DIM + n] = acc[i][j][r] + bpv;
    }
  }
}

extern "C" void kernel_launch(void* const* d_in, const int* in_sizes, int n_in,
                              void* d_out, int out_size, void* d_ws, size_t ws_size,
                              hipStream_t stream) {
  const float* x    = (const float*)d_in[0];
  const float* bias = (const float*)d_in[1];
  const float* Wq   = (const float*)d_in[2];
  const float* Wk   = (const float*)d_in[3];
  const float* Wv   = (const float*)d_in[4];
  const float* Wp   = (const float*)d_in[5];
  const float* bp   = (const float*)d_in[6];
  float* out = (float*)d_out;

  char* ws = (char*)d_ws;
  short* xb  = (short*)(ws);                    // 8192*768 bf16
  short* wqb = (short*)(ws + 12582912);
  short* wkb = (short*)(ws + 13762560);
  short* wvb = (short*)(ws + 14942208);
  short* wpb = (short*)(ws + 16121856);
  short* Qh  = (short*)(ws + 17301504);         // [b][h][n][64]
  short* Kh  = (short*)(ws + 29884416);
  short* Vt  = (short*)(ws + 42467328);         // [b][h][64][n]
  short* Ob  = (short*)(ws + 55050240);         // [b][n][768]

  cvt_x<<<6144, 256, 0, stream>>>(x, xb);
  cvt_w<<<dim3(576, 4), 256, 0, stream>>>(Wq, Wk, Wv, Wp, wqb, wkb, wvb, wpb);
  gemm_qkv<<<dim3(6, 64, 3), 256, 0, stream>>>(xb, wqb, wkb, wvb, Qh, Kh, Vt);
  attn_fused<<<768, 256, 0, stream>>>(Qh, Kh, Vt, bias, Ob);
  gemm_proj<<<dim3(6, 64), 256, 0, stream>>>(Ob, wpb, bp, out);
}